// Round 1
// baseline (300.820 us; speedup 1.0000x reference)
//
#include <hip/hip_runtime.h>
#include <hip/hip_fp16.h>

// Problem constants
#define HH 1080
#define WW 1920
#define NB 8
#define HWP (HH*WW)          // 2,073,600
#define NPX (NB*HWP)         // 16,588,800
#define NCX (WW/2)           // 960 half2 columns

// reflect index (jnp.pad 'reflect'): -k -> k ; H-1+k -> H-1-k
__device__ __forceinline__ int reflH(int y){ int r = y < 0 ? -y : y; return r >= HH ? 2*HH-2-r : r; }
__device__ __forceinline__ int reflW(int x){ int r = x < 0 ? -x : x; return r >= WW ? 2*WW-2-r : r; }

// ---------------------------------------------------------------- K1: dark channel
__global__ __launch_bounds__(256) void k_dark(const float* __restrict__ I, __half* __restrict__ dark){
    int q = blockIdx.x*blockDim.x + threadIdx.x;
    if (q >= NPX/4) return;
    int base = q*4;
    int b = base / HWP;
    int p = base - b*HWP;
    const float* src = I + (size_t)b*3*HWP + p;
    float4 c0 = *(const float4*)(src);
    float4 c1 = *(const float4*)(src + HWP);
    float4 c2 = *(const float4*)(src + 2*HWP);
    float m0 = fminf(fminf(c0.x, c1.x), c2.x);
    float m1 = fminf(fminf(c0.y, c1.y), c2.y);
    float m2 = fminf(fminf(c0.z, c1.z), c2.z);
    float m3 = fminf(fminf(c0.w, c1.w), c2.w);
    __half2* dst = (__half2*)(dark + base);
    dst[0] = __floats2half2_rn(m0, m1);
    dst[1] = __floats2half2_rn(m2, m3);
}

// ---------------------------------------------------------------- K2: erosion vertical (window 15, inf border)
#define EV_T 60   // 1080/60 = 18 tiles
__global__ __launch_bounds__(256) void k_erosv(const __half* __restrict__ in, __half* __restrict__ out){
    int t = blockIdx.x*blockDim.x + threadIdx.x;
    if (t >= NCX*NB*(HH/EV_T)) return;
    int cx = t % NCX;
    int r  = t / NCX;
    int b  = r % NB;
    int y0 = (r / NB) * EV_T;
    const __half2* src = (const __half2*)(in  + (size_t)b*HWP) + cx;
    __half2*       dst = (__half2*)(out + (size_t)b*HWP) + cx;
    float2 w[15];
    #pragma unroll
    for (int k = 0; k < 14; ++k){
        int y = y0 - 7 + k;
        if (y >= 0 && y < HH) w[k] = __half22float2(src[(size_t)y*NCX]);
        else { w[k].x = 1e5f; w[k].y = 1e5f; }
    }
    for (int y = y0; y < y0 + EV_T; ++y){
        int yn = y + 7;
        if (yn < HH) w[14] = __half22float2(src[(size_t)yn*NCX]);
        else { w[14].x = 1e5f; w[14].y = 1e5f; }
        float ax[8], ay[8];
        #pragma unroll
        for (int k = 0; k < 7; ++k){ ax[k] = fminf(w[2*k].x, w[2*k+1].x); ay[k] = fminf(w[2*k].y, w[2*k+1].y); }
        ax[7] = w[14].x; ay[7] = w[14].y;
        #pragma unroll
        for (int k = 0; k < 4; ++k){ ax[k] = fminf(ax[k], ax[k+4]); ay[k] = fminf(ay[k], ay[k+4]); }
        float mx = fminf(fminf(ax[0], ax[1]), fminf(ax[2], ax[3]));
        float my = fminf(fminf(ay[0], ay[1]), fminf(ay[2], ay[3]));
        dst[(size_t)y*NCX] = __floats2half2_rn(mx, my);
        #pragma unroll
        for (int k = 0; k < 14; ++k) w[k] = w[k+1];
    }
}

// ---------------------------------------------------------------- K3: erosion horizontal
__global__ __launch_bounds__(256) void k_erosh(const __half* __restrict__ in, __half* __restrict__ out){
    __shared__ __half2 lds[264];
    int bid = blockIdx.x;
    int seg = bid & 3;
    int y   = (bid >> 2) % HH;
    int b   = bid / (4*HH);
    int seg0 = seg * 512;
    const __half* row = in + (size_t)b*HWP + (size_t)y*WW;
    int tid = threadIdx.x;
    for (int slot = tid; slot < 264; slot += 256){
        int x = seg0 - 8 + 2*slot;
        __half2 v;
        if (x >= 0 && x + 1 < WW) v = *(const __half2*)(row + x);
        else {
            float lo = (x   >= 0 && x   < WW) ? __half2float(row[x])   : 1e5f;
            float hi = (x+1 >= 0 && x+1 < WW) ? __half2float(row[x+1]) : 1e5f;
            v = __floats2half2_rn(lo, hi);
        }
        lds[slot] = v;
    }
    __syncthreads();
    int x0 = seg0 + 2*tid;
    if (x0 >= WW) return;
    float v[18];
    #pragma unroll
    for (int k = 0; k < 9; ++k){
        float2 f = __half22float2(lds[tid + k]);
        v[2*k] = f.x; v[2*k+1] = f.y;
    }
    float c = v[2];
    #pragma unroll
    for (int k = 3; k <= 15; ++k) c = fminf(c, v[k]);
    float o0 = fminf(c, v[1]);
    float o1 = fminf(c, v[16]);
    *(__half2*)(out + (size_t)b*HWP + (size_t)y*WW + x0) = __floats2half2_rn(o0, o1);
}

// ---------------------------------------------------------------- K4: vertical box mean of {dim, dark, dim*dark, dim*dim}
#define BV_T 54   // 1080/54 = 20 tiles
__global__ __launch_bounds__(256) void k_blurv4(const __half* __restrict__ pdim, const __half* __restrict__ pdark,
                                                __half* __restrict__ v0, __half* __restrict__ v1,
                                                __half* __restrict__ v2, __half* __restrict__ v3){
    int t = blockIdx.x*blockDim.x + threadIdx.x;
    if (t >= NCX*NB*(HH/BV_T)) return;
    int cx = t % NCX;
    int r  = t / NCX;
    int b  = r % NB;
    int y0 = (r / NB) * BV_T;
    size_t pb = (size_t)b*HWP;
    const __half2* pd = (const __half2*)(pdim  + pb) + cx;
    const __half2* pk = (const __half2*)(pdark + pb) + cx;
    __half2* o0 = (__half2*)(v0 + pb) + cx;
    __half2* o1 = (__half2*)(v1 + pb) + cx;
    __half2* o2 = (__half2*)(v2 + pb) + cx;
    __half2* o3 = (__half2*)(v3 + pb) + cx;

    float si0=0,si1=0,sp0=0,sp1=0,sip0=0,sip1=0,sii0=0,sii1=0;
    auto acc = [&](int yy, float sg){
        int yr = reflH(yy);
        float2 di = __half22float2(pd[(size_t)yr*NCX]);
        float2 dk = __half22float2(pk[(size_t)yr*NCX]);
        si0  += sg*di.x;        si1  += sg*di.y;
        sp0  += sg*dk.x;        sp1  += sg*dk.y;
        sip0 += sg*(di.x*dk.x); sip1 += sg*(di.y*dk.y);
        sii0 += sg*(di.x*di.x); sii1 += sg*(di.y*di.y);
    };
    const float inv = 1.0f/60.0f;
    for (int k = -29; k <= 30; ++k) acc(y0 + k, 1.0f);
    size_t off = (size_t)y0*NCX;
    o0[off] = __floats2half2_rn(si0*inv,  si1*inv);
    o1[off] = __floats2half2_rn(sp0*inv,  sp1*inv);
    o2[off] = __floats2half2_rn(sip0*inv, sip1*inv);
    o3[off] = __floats2half2_rn(sii0*inv, sii1*inv);
    for (int y = y0 + 1; y < y0 + BV_T; ++y){
        acc(y + 30, 1.0f);
        acc(y - 30, -1.0f);
        off = (size_t)y*NCX;
        o0[off] = __floats2half2_rn(si0*inv,  si1*inv);
        o1[off] = __floats2half2_rn(sp0*inv,  sp1*inv);
        o2[off] = __floats2half2_rn(sip0*inv, sip1*inv);
        o3[off] = __floats2half2_rn(sii0*inv, sii1*inv);
    }
}

// ---------------------------------------------------------------- K6: vertical box mean of {a, b}
__global__ __launch_bounds__(256) void k_blurv2(const __half* __restrict__ pa, const __half* __restrict__ pbf,
                                                __half* __restrict__ va, __half* __restrict__ vb){
    int t = blockIdx.x*blockDim.x + threadIdx.x;
    if (t >= NCX*NB*(HH/BV_T)) return;
    int cx = t % NCX;
    int r  = t / NCX;
    int b  = r % NB;
    int y0 = (r / NB) * BV_T;
    size_t pbase = (size_t)b*HWP;
    const __half2* p0 = (const __half2*)(pa  + pbase) + cx;
    const __half2* p1 = (const __half2*)(pbf + pbase) + cx;
    __half2* o0 = (__half2*)(va + pbase) + cx;
    __half2* o1 = (__half2*)(vb + pbase) + cx;
    float sa0=0,sa1=0,sb0=0,sb1=0;
    auto acc = [&](int yy, float sg){
        int yr = reflH(yy);
        float2 fa = __half22float2(p0[(size_t)yr*NCX]);
        float2 fb = __half22float2(p1[(size_t)yr*NCX]);
        sa0 += sg*fa.x; sa1 += sg*fa.y;
        sb0 += sg*fb.x; sb1 += sg*fb.y;
    };
    const float inv = 1.0f/60.0f;
    for (int k = -29; k <= 30; ++k) acc(y0 + k, 1.0f);
    size_t off = (size_t)y0*NCX;
    o0[off] = __floats2half2_rn(sa0*inv, sa1*inv);
    o1[off] = __floats2half2_rn(sb0*inv, sb1*inv);
    for (int y = y0 + 1; y < y0 + BV_T; ++y){
        acc(y + 30, 1.0f);
        acc(y - 30, -1.0f);
        off = (size_t)y*NCX;
        o0[off] = __floats2half2_rn(sa0*inv, sa1*inv);
        o1[off] = __floats2half2_rn(sb0*inv, sb1*inv);
    }
}

// LDS pad: +1 word every 32 -> stride-16-thread access becomes 2-way (free)
#define PADI(e) ((e) + ((e) >> 5))

// ---------------------------------------------------------------- K5: horizontal box mean x4 + a,b
__global__ __launch_bounds__(128) void k_blurh4(const __half* __restrict__ v0, const __half* __restrict__ v1,
                                                const __half* __restrict__ v2, const __half* __restrict__ v3,
                                                __half* __restrict__ pa, __half* __restrict__ pbf){
    __shared__ float lds[4][2048];
    int bid = blockIdx.x;
    int y = bid % HH;
    int b = bid / HH;
    size_t rb = (size_t)b*HWP + (size_t)y*WW;
    const __half* p0 = v0 + rb; const __half* p1 = v1 + rb;
    const __half* p2 = v2 + rb; const __half* p3 = v3 + rb;
    int tid = threadIdx.x;
    for (int e = tid; e < 1979; e += 128){
        int x = reflW(e - 29);
        int pe = PADI(e);
        lds[0][pe] = __half2float(p0[x]);
        lds[1][pe] = __half2float(p1[x]);
        lds[2][pe] = __half2float(p2[x]);
        lds[3][pe] = __half2float(p3[x]);
    }
    __syncthreads();
    if (tid >= 120) return;
    int x0 = tid * 16;
    float s0=0, s1=0, s2=0, s3=0;
    for (int k = 0; k < 60; ++k){
        int pe = PADI(x0 + k);
        s0 += lds[0][pe]; s1 += lds[1][pe]; s2 += lds[2][pe]; s3 += lds[3][pe];
    }
    const float inv = 1.0f/60.0f;
    __half2 ha[8], hb[8];
    float prev_a = 0.f, prev_b = 0.f;
    #pragma unroll
    for (int j = 0; j < 16; ++j){
        if (j > 0){
            int pe1 = PADI(x0 + j + 59), pe0 = PADI(x0 + j - 1);
            s0 += lds[0][pe1] - lds[0][pe0];
            s1 += lds[1][pe1] - lds[1][pe0];
            s2 += lds[2][pe1] - lds[2][pe0];
            s3 += lds[3][pe1] - lds[3][pe0];
        }
        float mI  = s0*inv, mP = s1*inv, mIp = s2*inv, mII = s3*inv;
        float cov = mIp - mI*mP;
        float var = mII - mI*mI;
        float a   = cov / (var + 1e-4f);
        float bb  = mP - a*mI;
        if (j & 1){
            ha[j>>1] = __floats2half2_rn(prev_a, a);
            hb[j>>1] = __floats2half2_rn(prev_b, bb);
        } else { prev_a = a; prev_b = bb; }
    }
    *(uint4*)(pa  + rb + x0)     = *(uint4*)&ha[0];
    *(uint4*)(pa  + rb + x0 + 8) = *(uint4*)&ha[4];
    *(uint4*)(pbf + rb + x0)     = *(uint4*)&hb[0];
    *(uint4*)(pbf + rb + x0 + 8) = *(uint4*)&hb[4];
}

// ---------------------------------------------------------------- K7: horizontal box mean x2 + q = ma*dim + mb
__global__ __launch_bounds__(128) void k_blurh2(const __half* __restrict__ va, const __half* __restrict__ vb,
                                                const __half* __restrict__ pdim, float* __restrict__ qout){
    __shared__ float lds[2][2048];
    int bid = blockIdx.x;
    int y = bid % HH;
    int b = bid / HH;
    size_t rb = (size_t)b*HWP + (size_t)y*WW;
    const __half* p0 = va + rb; const __half* p1 = vb + rb;
    int tid = threadIdx.x;
    for (int e = tid; e < 1979; e += 128){
        int x = reflW(e - 29);
        int pe = PADI(e);
        lds[0][pe] = __half2float(p0[x]);
        lds[1][pe] = __half2float(p1[x]);
    }
    __syncthreads();
    if (tid >= 120) return;
    int x0 = tid * 16;
    float sa=0, sb=0;
    for (int k = 0; k < 60; ++k){
        int pe = PADI(x0 + k);
        sa += lds[0][pe]; sb += lds[1][pe];
    }
    const float inv = 1.0f/60.0f;
    float qv[16];
    #pragma unroll
    for (int j = 0; j < 16; ++j){
        if (j > 0){
            int pe1 = PADI(x0 + j + 59), pe0 = PADI(x0 + j - 1);
            sa += lds[0][pe1] - lds[0][pe0];
            sb += lds[1][pe1] - lds[1][pe0];
        }
        float dv = __half2float(pdim[rb + x0 + j]);
        qv[j] = (sa*inv)*dv + (sb*inv);
    }
    #pragma unroll
    for (int m = 0; m < 4; ++m){
        *(float4*)(qout + rb + x0 + 4*m) = make_float4(qv[4*m], qv[4*m+1], qv[4*m+2], qv[4*m+3]);
    }
}

// ---------------------------------------------------------------- launch
extern "C" void kernel_launch(void* const* d_in, const int* in_sizes, int n_in,
                              void* d_out, int out_size, void* d_ws, size_t ws_size,
                              hipStream_t stream){
    const float* I = (const float*)d_in[0];
    float* qout = (float*)d_out;
    __half* ws = (__half*)d_ws;

    // 7 f16 planes of NPX elements each (~232 MB total)
    __half* p_dark = ws;
    __half* p_tmp  = ws + (size_t)NPX;      // erosV out, later reused for b
    __half* p_dim  = ws + 2*(size_t)NPX;
    __half* p_v0   = ws + 3*(size_t)NPX;
    __half* p_v1   = ws + 4*(size_t)NPX;
    __half* p_v2   = ws + 5*(size_t)NPX;
    __half* p_v3   = ws + 6*(size_t)NPX;
    __half* p_a    = p_dark;   // dark dead after k_blurv4
    __half* p_b    = p_tmp;    // tmp dead after k_erosh
    __half* p_va   = p_v0;     // v-planes dead after k_blurh4
    __half* p_vb   = p_v1;

    k_dark  <<<NPX/4/256, 256, 0, stream>>>(I, p_dark);
    k_erosv <<<(NCX*NB*(HH/EV_T))/256, 256, 0, stream>>>(p_dark, p_tmp);
    k_erosh <<<NB*HH*4, 256, 0, stream>>>(p_tmp, p_dim);
    k_blurv4<<<(NCX*NB*(HH/BV_T))/256, 256, 0, stream>>>(p_dim, p_dark, p_v0, p_v1, p_v2, p_v3);
    k_blurh4<<<NB*HH, 128, 0, stream>>>(p_v0, p_v1, p_v2, p_v3, p_a, p_b);
    k_blurv2<<<(NCX*NB*(HH/BV_T))/256, 256, 0, stream>>>(p_a, p_b, p_va, p_vb);
    k_blurh2<<<NB*HH, 128, 0, stream>>>(p_va, p_vb, p_dim, qout);
}